// Round 5
// baseline (225.145 us; speedup 1.0000x reference)
//
#include <hip/hip_runtime.h>
#include <hip/hip_bf16.h>

// MultiHeadSelfAttention  B=2, S=4096, D=512, H=8, dk=64
// R5: attn wave M-tile 32->64 q-rows (block=256 rows, grid 256 = 1 block/CU):
//     K/V frag reads + staging invariant in M -> LDS traffic per FLOP -33%.
//     launch_bounds(256,1): 1 wave/SIMD, VGPR budget 512 (no squeeze).
// Key permutation pi(kk)=(kk&15)*4+(kk>>4) on key axis of P (LDS) and V^T
// (global) -> packed b64 P stores; PV invariant under shared key permutation.

#define DMODEL 512
#define SEQ    4096
#define NTOK   8192
#define LDQK   1024

using f32x4 = __attribute__((ext_vector_type(4))) float;
using s16x8 = __attribute__((ext_vector_type(8))) short;
using u16x8 = __attribute__((ext_vector_type(8))) unsigned short;

static __device__ __forceinline__ unsigned short f2bf(float f) {
  union { float f; unsigned u; } v; v.f = f;
  unsigned r = v.u + 0x7fff + ((v.u >> 16) & 1);   // RNE
  return (unsigned short)(r >> 16);
}

__global__ void cast_x_kernel(const float* __restrict__ x,
                              unsigned short* __restrict__ xb, int n4) {
  int i = blockIdx.x * blockDim.x + threadIdx.x;
  if (i >= n4) return;
  float4 v = ((const float4*)x)[i];
  ushort4 o;
  o.x = f2bf(v.x); o.y = f2bf(v.y); o.z = f2bf(v.z); o.w = f2bf(v.w);
  ((ushort4*)xb)[i] = o;
}

// All four W transposes in one launch. Wall = [Wq'|Wk|Wv|Wo], each N-major.
__global__ void wtrans4_kernel(const float* __restrict__ Wq,
                               const float* __restrict__ Wk,
                               const float* __restrict__ Wv,
                               const float* __restrict__ Wo,
                               unsigned short* __restrict__ Wall, float c2) {
  int y = blockIdx.y;
  int idx = blockIdx.x * 256 + threadIdx.x;
  const float* W = (y == 0) ? Wq : (y == 1) ? Wk : (y == 2) ? Wv : Wo;
  float scale = (y == 0) ? c2 : 1.0f;
  int k = idx & 511, n = idx >> 9;
  Wall[y * 262144 + idx] = f2bf(W[k * 512 + n] * scale);
}

// Fused QK + V^T GEMM. grid (64, 12).
//  by 0..7 : QK block  — C[8192 x 1024] = xb @ [Wq'|Wk]^T, bf16 row-major.
//  by 8..11: V^T block — C[512 x 8192] = Wv_t @ xb^T, stored batched
//            [b][m=h*64+dk][s] with key-permuted s (pi within 64-groups).
__global__ __launch_bounds__(256, 3) void gemm_qkv(
    const unsigned short* __restrict__ xb,
    const unsigned short* __restrict__ Wall,
    unsigned short* __restrict__ QKb,
    unsigned short* __restrict__ Vtb)
{
  __shared__ unsigned short As[128 * 32];
  __shared__ unsigned short Bs[128 * 32];
  const int by = blockIdx.y;
  const bool vmode = (by >= 8);
  const unsigned short* A  = vmode ? (Wall + 2 * 262144) : xb;
  const unsigned short* Bt = vmode ? xb : Wall;
  const size_t bm = vmode ? (size_t)(by - 8) * 128 : (size_t)blockIdx.x * 128;
  const size_t bn = vmode ? (size_t)blockIdx.x * 128 : (size_t)by * 128;
  const int tid  = threadIdx.x;
  const int wave = tid >> 6, lane = tid & 63;
  const int q4 = lane >> 4, ln = lane & 15;
  const int wm = (wave >> 1) * 64, wn = (wave & 1) * 64;
  f32x4 acc[4][4] = {};
  const int srow = wave * 16 + (lane >> 2);
  const int scol = (lane & 3) * 8;

  u16x8 a0 = *(const u16x8*)(A  + (bm + srow)      * 512 + scol);
  u16x8 a1 = *(const u16x8*)(A  + (bm + 64 + srow) * 512 + scol);
  u16x8 b0 = *(const u16x8*)(Bt + (bn + srow)      * 512 + scol);
  u16x8 b1 = *(const u16x8*)(Bt + (bn + 64 + srow) * 512 + scol);

  for (int kt = 0; kt < 512; kt += 32) {
    __syncthreads();
    *(u16x8*)(As + srow * 32 + scol)        = a0;
    *(u16x8*)(As + (64 + srow) * 32 + scol) = a1;
    *(u16x8*)(Bs + srow * 32 + scol)        = b0;
    *(u16x8*)(Bs + (64 + srow) * 32 + scol) = b1;
    __syncthreads();
    if (kt + 32 < 512) {
      a0 = *(const u16x8*)(A  + (bm + srow)      * 512 + kt + 32 + scol);
      a1 = *(const u16x8*)(A  + (bm + 64 + srow) * 512 + kt + 32 + scol);
      b0 = *(const u16x8*)(Bt + (bn + srow)      * 512 + kt + 32 + scol);
      b1 = *(const u16x8*)(Bt + (bn + 64 + srow) * 512 + kt + 32 + scol);
    }
    s16x8 af[4], bfr[4];
#pragma unroll
    for (int i = 0; i < 4; i++)
      af[i] = *(const s16x8*)(As + (wm + i * 16 + ln) * 32 + q4 * 8);
#pragma unroll
    for (int i = 0; i < 4; i++)
      bfr[i] = *(const s16x8*)(Bs + (wn + i * 16 + ln) * 32 + q4 * 8);
#pragma unroll
    for (int mi = 0; mi < 4; mi++)
#pragma unroll
      for (int ni = 0; ni < 4; ni++)
        acc[mi][ni] = __builtin_amdgcn_mfma_f32_16x16x32_bf16(
            af[mi], bfr[ni], acc[mi][ni], 0, 0, 0);
  }
#pragma unroll
  for (int mi = 0; mi < 4; mi++)
#pragma unroll
    for (int r = 0; r < 4; ++r) {
      size_t row = bm + wm + mi * 16 + q4 * 4 + r;
#pragma unroll
      for (int ni = 0; ni < 4; ni++) {
        size_t col = bn + wn + ni * 16 + ln;
        unsigned short hv = f2bf(acc[mi][ni][r]);
        if (!vmode) {
          QKb[row * 1024 + col] = hv;
        } else {
          int b = (int)(col >> 12), s = (int)(col & 4095);
          int sp = (s & ~63) | ((s & 15) << 2) | ((s >> 4) & 3);   // pi(s%64)
          Vtb[(size_t)b * 2097152 + row * 4096 + sp] = hv;
        }
      }
    }
}

// Flash-lite attention. grid (16 qtiles x 256 rows, 8 heads, 2 batch) = 256.
// 4 waves x 64 q-rows (4 m-frags). Q pre-scaled: p = exp2(logit), no max,
// l reduced at end. P via permuted b64 stores; V^T global already permuted.
__global__ __launch_bounds__(256, 1) void attn_kernel(
    const unsigned short* __restrict__ QK,   // NTOK x 1024 [Q'|K]
    const unsigned short* __restrict__ Vt,   // [b*8+h][64 dk][4096 s-perm]
    unsigned short* __restrict__ Oc)         // NTOK x 512 concat
{
  const int qt = blockIdx.x, h = blockIdx.y, b = blockIdx.z;
  const int tid = threadIdx.x, wave = tid >> 6, lane = tid & 63;
  const int q4 = lane >> 4, ln = lane & 15;
  __shared__ unsigned short Ks[64 * 72];      // [key][dk]
  __shared__ unsigned short Vs[64 * 72];      // [dk][key-perm]
  __shared__ unsigned short Ps[4][64 * 72];   // per-wave P tile [qrow][key-perm]
  const size_t rowbase = (size_t)b * SEQ;
  const size_t qrow0   = (size_t)qt * 256 + wave * 64;
  const unsigned short* Kp  = QK + rowbase * LDQK + 512 + h * 64;
  const unsigned short* VTp = Vt + ((size_t)(b * 8 + h) * 64) * SEQ;

  s16x8 qf[4][2];
#pragma unroll
  for (int mf = 0; mf < 4; ++mf) {
    const unsigned short* q = QK + (rowbase + qrow0 + mf * 16 + ln) * LDQK + h * 64;
    qf[mf][0] = *(const s16x8*)(q + q4 * 8);
    qf[mf][1] = *(const s16x8*)(q + 32 + q4 * 8);
  }
  f32x4 o[4][4] = {};
  float lp[4][4] = {};

  const int srow = tid >> 2;              // 0..63
  const int scol = (tid & 3) * 16;        // 0,16,32,48

  const unsigned short* kgp = Kp  + (size_t)srow * LDQK + scol;
  const unsigned short* vgp = VTp + (size_t)srow * SEQ  + scol;
  u16x8 kr  = *(const u16x8*)kgp;
  u16x8 kr2 = *(const u16x8*)(kgp + 8);
  u16x8 vr  = *(const u16x8*)vgp;
  u16x8 vr2 = *(const u16x8*)(vgp + 8);

  for (int t = 0; t < SEQ / 64; ++t) {
    __syncthreads();
    *(u16x8*)(Ks + srow * 72 + scol)     = kr;
    *(u16x8*)(Ks + srow * 72 + scol + 8) = kr2;
    *(u16x8*)(Vs + srow * 72 + scol)     = vr;
    *(u16x8*)(Vs + srow * 72 + scol + 8) = vr2;
    __syncthreads();
    if (t + 1 < SEQ / 64) {               // register prefetch of next tile
      kgp += (size_t)64 * LDQK;
      vgp += 64;
      kr  = *(const u16x8*)kgp;
      kr2 = *(const u16x8*)(kgp + 8);
      vr  = *(const u16x8*)vgp;
      vr2 = *(const u16x8*)(vgp + 8);
    }
    // S = Q' K^T: K-frags shared across all 4 m-frags
    f32x4 s4[4][4] = {};
#pragma unroll
    for (int ni = 0; ni < 4; ni++) {
      const unsigned short* kb = Ks + (ni * 16 + ln) * 72 + q4 * 8;
      s16x8 kf0 = *(const s16x8*)kb;
      s16x8 kf1 = *(const s16x8*)(kb + 32);
#pragma unroll
      for (int mf = 0; mf < 4; ++mf) {
        s4[mf][ni] = __builtin_amdgcn_mfma_f32_16x16x32_bf16(qf[mf][0], kf0, s4[mf][ni], 0, 0, 0);
        s4[mf][ni] = __builtin_amdgcn_mfma_f32_16x16x32_bf16(qf[mf][1], kf1, s4[mf][ni], 0, 0, 0);
      }
    }
    // p = exp2(s); keys {ln,16+ln,32+ln,48+ln} -> perm cols {4ln..4ln+3}
    unsigned short* Pw = Ps[wave];
#pragma unroll
    for (int mf = 0; mf < 4; ++mf)
#pragma unroll
      for (int r = 0; r < 4; ++r) {
        float p0 = __builtin_amdgcn_exp2f(s4[mf][0][r]);
        float p1 = __builtin_amdgcn_exp2f(s4[mf][1][r]);
        float p2 = __builtin_amdgcn_exp2f(s4[mf][2][r]);
        float p3 = __builtin_amdgcn_exp2f(s4[mf][3][r]);
        lp[mf][r] += (p0 + p1) + (p2 + p3);
        __hip_bfloat162 lo = __float22bfloat162_rn(make_float2(p0, p1));
        __hip_bfloat162 hi = __float22bfloat162_rn(make_float2(p2, p3));
        uint2 w;
        w.x = *(unsigned*)&lo;
        w.y = *(unsigned*)&hi;
        *(uint2*)(Pw + (mf * 16 + q4 * 4 + r) * 72 + ln * 4) = w;
      }
    // O += P V  (both key-permuted identically); V-frags shared across m-frags
#pragma unroll
    for (int ks = 0; ks < 2; ++ks) {
      s16x8 pf[4];
#pragma unroll
      for (int mf = 0; mf < 4; ++mf)
        pf[mf] = *(const s16x8*)(Pw + (mf * 16 + ln) * 72 + ks * 32 + q4 * 8);
#pragma unroll
      for (int ni = 0; ni < 4; ni++) {
        s16x8 vf = *(const s16x8*)(Vs + (ni * 16 + ln) * 72 + ks * 32 + q4 * 8);
#pragma unroll
        for (int mf = 0; mf < 4; ++mf)
          o[mf][ni] = __builtin_amdgcn_mfma_f32_16x16x32_bf16(pf[mf], vf, o[mf][ni], 0, 0, 0);
      }
    }
  }
#pragma unroll
  for (int mf = 0; mf < 4; ++mf)
#pragma unroll
    for (int r = 0; r < 4; ++r) {
      float l = lp[mf][r];
#pragma unroll
      for (int off = 1; off < 16; off <<= 1)
        l += __shfl_xor(l, off, 64);
      float inv = 1.0f / l;
      size_t row = rowbase + qrow0 + mf * 16 + q4 * 4 + r;
#pragma unroll
      for (int ni = 0; ni < 4; ni++)
        Oc[row * DMODEL + h * 64 + ni * 16 + ln] = f2bf(o[mf][ni][r] * inv);
    }
}

// out = Oc @ Wo^T : M=8192 N=512 K=512, tile 128x64 (512 blocks = 2/CU), f32.
__global__ __launch_bounds__(256, 3) void gemm_out(
    const unsigned short* __restrict__ A,
    const unsigned short* __restrict__ Bt,
    float* __restrict__ C)
{
  __shared__ unsigned short As[128 * 32];
  __shared__ unsigned short Bs[64 * 32];
  const int tid  = threadIdx.x;
  const int wave = tid >> 6, lane = tid & 63;
  const int q4 = lane >> 4, ln = lane & 15;
  const size_t bm = (size_t)blockIdx.x * 128;
  const size_t bn = (size_t)blockIdx.y * 64;
  const int wm = (wave >> 1) * 64, wn = (wave & 1) * 32;
  f32x4 acc[4][2] = {};
  const int srow = wave * 16 + (lane >> 2);
  const int scol = (lane & 3) * 8;

  u16x8 a0 = *(const u16x8*)(A  + (bm + srow)      * 512 + scol);
  u16x8 a1 = *(const u16x8*)(A  + (bm + 64 + srow) * 512 + scol);
  u16x8 b0 = *(const u16x8*)(Bt + (bn + srow)      * 512 + scol);

  for (int kt = 0; kt < 512; kt += 32) {
    __syncthreads();
    *(u16x8*)(As + srow * 32 + scol)        = a0;
    *(u16x8*)(As + (64 + srow) * 32 + scol) = a1;
    *(u16x8*)(Bs + srow * 32 + scol)        = b0;
    __syncthreads();
    if (kt + 32 < 512) {
      a0 = *(const u16x8*)(A  + (bm + srow)      * 512 + kt + 32 + scol);
      a1 = *(const u16x8*)(A  + (bm + 64 + srow) * 512 + kt + 32 + scol);
      b0 = *(const u16x8*)(Bt + (bn + srow)      * 512 + kt + 32 + scol);
    }
    s16x8 af[4], bfr[2];
#pragma unroll
    for (int i = 0; i < 4; i++)
      af[i] = *(const s16x8*)(As + (wm + i * 16 + ln) * 32 + q4 * 8);
#pragma unroll
    for (int i = 0; i < 2; i++)
      bfr[i] = *(const s16x8*)(Bs + (wn + i * 16 + ln) * 32 + q4 * 8);
#pragma unroll
    for (int mi = 0; mi < 4; mi++)
#pragma unroll
      for (int ni = 0; ni < 2; ni++)
        acc[mi][ni] = __builtin_amdgcn_mfma_f32_16x16x32_bf16(
            af[mi], bfr[ni], acc[mi][ni], 0, 0, 0);
  }
#pragma unroll
  for (int mi = 0; mi < 4; mi++)
#pragma unroll
    for (int r = 0; r < 4; ++r) {
      size_t row = bm + wm + mi * 16 + q4 * 4 + r;
#pragma unroll
      for (int ni = 0; ni < 2; ni++)
        C[row * 512 + bn + wn + ni * 16 + ln] = acc[mi][ni][r];
    }
}

extern "C" void kernel_launch(void* const* d_in, const int* in_sizes, int n_in,
                              void* d_out, int out_size, void* d_ws, size_t ws_size,
                              hipStream_t stream) {
  const float* x  = (const float*)d_in[0];
  const float* Wq = (const float*)d_in[1];
  const float* Wk = (const float*)d_in[2];
  const float* Wv = (const float*)d_in[3];
  const float* Wo = (const float*)d_in[4];

  char* ws = (char*)d_ws;
  unsigned short* xb   = (unsigned short*)(ws);              //  8,388,608
  unsigned short* Wall = (unsigned short*)(ws + 8388608);    //  2,097,152
  unsigned short* QKb  = (unsigned short*)(ws + 10485760);   // 16,777,216
  unsigned short* Vtb  = (unsigned short*)(ws + 27262976);   //  8,388,608
  unsigned short* Oc   = (unsigned short*)(ws + 35651584);   //  8,388,608

  const float C2 = 0.125f * 1.44269504088896f;  // 1/sqrt(64) * log2(e)

  hipLaunchKernelGGL(cast_x_kernel, dim3(NTOK * DMODEL / 4 / 256), dim3(256), 0,
                     stream, x, xb, NTOK * DMODEL / 4);
  hipLaunchKernelGGL(wtrans4_kernel, dim3(1024, 4), dim3(256), 0, stream,
                     Wq, Wk, Wv, Wo, Wall, C2);
  hipLaunchKernelGGL(gemm_qkv, dim3(64, 12), dim3(256), 0, stream,
                     xb, Wall, QKb, Vtb);
  hipLaunchKernelGGL(attn_kernel, dim3(16, 8, 2), dim3(256), 0, stream,
                     QKb, Vtb, Oc);
  hipLaunchKernelGGL(gemm_out, dim3(64, 8), dim3(256), 0, stream,
                     Oc, Wall + 3 * 262144, (float*)d_out);
}

// Round 6
// 206.407 us; speedup vs baseline: 1.0908x; 1.0908x over previous
//
#include <hip/hip_runtime.h>
#include <hip/hip_bf16.h>

// MultiHeadSelfAttention  B=2, S=4096, D=512, H=8, dk=64
// R6: revert attn tiling to R4 (M=32/wave, 512 blocks, 2 waves/SIMD — R5 showed
//     M=64 => 1 wave/SIMD kills latency hiding). NEW: compute S^T = K*Q^T so
//     each lane's C-output holds P-values for its OWN q-row (q=ln); with key
//     permutation kappa baked into V^T's global layout, P packs directly into
//     PV A-fragments in registers -> P LDS round-trip fully eliminated.
// kappa(m) = 32*(m>>5) + 8*((m>>2)&3) + 4*((m>>4)&1) + (m&3)  per 64-key group.

#define DMODEL 512
#define SEQ    4096
#define NTOK   8192
#define LDQK   1024

using f32x4 = __attribute__((ext_vector_type(4))) float;
using s16x8 = __attribute__((ext_vector_type(8))) short;
using u16x8 = __attribute__((ext_vector_type(8))) unsigned short;

static __device__ __forceinline__ unsigned short f2bf(float f) {
  union { float f; unsigned u; } v; v.f = f;
  unsigned r = v.u + 0x7fff + ((v.u >> 16) & 1);   // RNE
  return (unsigned short)(r >> 16);
}

static __device__ __forceinline__ unsigned pack_bf2(float lo, float hi) {
  __hip_bfloat162 t = __float22bfloat162_rn(make_float2(lo, hi));
  union { __hip_bfloat162 b; unsigned u; } c; c.b = t; return c.u;
}

__global__ void cast_x_kernel(const float* __restrict__ x,
                              unsigned short* __restrict__ xb, int n4) {
  int i = blockIdx.x * blockDim.x + threadIdx.x;
  if (i >= n4) return;
  float4 v = ((const float4*)x)[i];
  ushort4 o;
  o.x = f2bf(v.x); o.y = f2bf(v.y); o.z = f2bf(v.z); o.w = f2bf(v.w);
  ((ushort4*)xb)[i] = o;
}

// All four W transposes in one launch. Wall = [Wq'|Wk|Wv|Wo], each N-major.
__global__ void wtrans4_kernel(const float* __restrict__ Wq,
                               const float* __restrict__ Wk,
                               const float* __restrict__ Wv,
                               const float* __restrict__ Wo,
                               unsigned short* __restrict__ Wall, float c2) {
  int y = blockIdx.y;
  int idx = blockIdx.x * 256 + threadIdx.x;
  const float* W = (y == 0) ? Wq : (y == 1) ? Wk : (y == 2) ? Wv : Wo;
  float scale = (y == 0) ? c2 : 1.0f;
  int k = idx & 511, n = idx >> 9;
  Wall[y * 262144 + idx] = f2bf(W[k * 512 + n] * scale);
}

// Fused QK + V^T GEMM. grid (64, 12).
//  by 0..7 : QK block  — C[8192 x 1024] = xb @ [Wq'|Wk]^T, bf16 row-major.
//  by 8..11: V^T block — C[512 x 8192] = Wv_t @ xb^T, stored batched
//            [b][m=h*64+dk][s] with kappa-permuted s within 64-groups.
__global__ __launch_bounds__(256, 3) void gemm_qkv(
    const unsigned short* __restrict__ xb,
    const unsigned short* __restrict__ Wall,
    unsigned short* __restrict__ QKb,
    unsigned short* __restrict__ Vtb)
{
  __shared__ unsigned short As[128 * 32];
  __shared__ unsigned short Bs[128 * 32];
  const int by = blockIdx.y;
  const bool vmode = (by >= 8);
  const unsigned short* A  = vmode ? (Wall + 2 * 262144) : xb;
  const unsigned short* Bt = vmode ? xb : Wall;
  const size_t bm = vmode ? (size_t)(by - 8) * 128 : (size_t)blockIdx.x * 128;
  const size_t bn = vmode ? (size_t)blockIdx.x * 128 : (size_t)by * 128;
  const int tid  = threadIdx.x;
  const int wave = tid >> 6, lane = tid & 63;
  const int q4 = lane >> 4, ln = lane & 15;
  const int wm = (wave >> 1) * 64, wn = (wave & 1) * 64;
  f32x4 acc[4][4] = {};
  const int srow = wave * 16 + (lane >> 2);
  const int scol = (lane & 3) * 8;

  u16x8 a0 = *(const u16x8*)(A  + (bm + srow)      * 512 + scol);
  u16x8 a1 = *(const u16x8*)(A  + (bm + 64 + srow) * 512 + scol);
  u16x8 b0 = *(const u16x8*)(Bt + (bn + srow)      * 512 + scol);
  u16x8 b1 = *(const u16x8*)(Bt + (bn + 64 + srow) * 512 + scol);

  for (int kt = 0; kt < 512; kt += 32) {
    __syncthreads();
    *(u16x8*)(As + srow * 32 + scol)        = a0;
    *(u16x8*)(As + (64 + srow) * 32 + scol) = a1;
    *(u16x8*)(Bs + srow * 32 + scol)        = b0;
    *(u16x8*)(Bs + (64 + srow) * 32 + scol) = b1;
    __syncthreads();
    if (kt + 32 < 512) {
      a0 = *(const u16x8*)(A  + (bm + srow)      * 512 + kt + 32 + scol);
      a1 = *(const u16x8*)(A  + (bm + 64 + srow) * 512 + kt + 32 + scol);
      b0 = *(const u16x8*)(Bt + (bn + srow)      * 512 + kt + 32 + scol);
      b1 = *(const u16x8*)(Bt + (bn + 64 + srow) * 512 + kt + 32 + scol);
    }
    s16x8 af[4], bfr[4];
#pragma unroll
    for (int i = 0; i < 4; i++)
      af[i] = *(const s16x8*)(As + (wm + i * 16 + ln) * 32 + q4 * 8);
#pragma unroll
    for (int i = 0; i < 4; i++)
      bfr[i] = *(const s16x8*)(Bs + (wn + i * 16 + ln) * 32 + q4 * 8);
#pragma unroll
    for (int mi = 0; mi < 4; mi++)
#pragma unroll
      for (int ni = 0; ni < 4; ni++)
        acc[mi][ni] = __builtin_amdgcn_mfma_f32_16x16x32_bf16(
            af[mi], bfr[ni], acc[mi][ni], 0, 0, 0);
  }
#pragma unroll
  for (int mi = 0; mi < 4; mi++)
#pragma unroll
    for (int r = 0; r < 4; ++r) {
      size_t row = bm + wm + mi * 16 + q4 * 4 + r;
#pragma unroll
      for (int ni = 0; ni < 4; ni++) {
        size_t col = bn + wn + ni * 16 + ln;
        unsigned short hv = f2bf(acc[mi][ni][r]);
        if (!vmode) {
          QKb[row * 1024 + col] = hv;
        } else {
          int b = (int)(col >> 12), s = (int)(col & 4095);
          // kappa(s%64): position holding key s for PV A-frag alignment
          int sp = (s & ~63) | (s & 32) | (((s >> 2) & 3) << 3) |
                   (((s >> 4) & 1) << 2) | (s & 3);
          Vtb[(size_t)b * 2097152 + row * 4096 + sp] = hv;
        }
      }
    }
}

// Flash-lite attention. grid (32 qtiles x 128 rows, 8 heads, 2 batch) = 512.
// 4 waves x 32 q-rows. Computes S^T = K*Q^T: lane (ln,q4) holds P for q=ln,
// key-pos 16ni+4q4+r -> packs in-register into PV A-frags (kappa-aligned V).
// Q pre-scaled: p = exp2(logit), no max; l reduced once at end.
__global__ __launch_bounds__(256, 2) void attn_kernel(
    const unsigned short* __restrict__ QK,   // NTOK x 1024 [Q'|K]
    const unsigned short* __restrict__ Vt,   // [b*8+h][64 dk][4096 s-kappa]
    unsigned short* __restrict__ Oc)         // NTOK x 512 concat
{
  const int qt = blockIdx.x, h = blockIdx.y, b = blockIdx.z;
  const int tid = threadIdx.x, wave = tid >> 6, lane = tid & 63;
  const int q4 = lane >> 4, ln = lane & 15;
  __shared__ unsigned short Ks[64 * 72];      // [key][dk]
  __shared__ unsigned short Vs[64 * 72];      // [dk][key-kappa]
  const size_t rowbase = (size_t)b * SEQ;
  const size_t qrow0   = (size_t)qt * 128 + wave * 32;
  const unsigned short* Kp  = QK + rowbase * LDQK + 512 + h * 64;
  const unsigned short* VTp = Vt + ((size_t)(b * 8 + h) * 64) * SEQ;

  s16x8 qf[2][2];   // B-frags: B[n=ln (q)][k=q4*8+j]
#pragma unroll
  for (int mf = 0; mf < 2; ++mf) {
    const unsigned short* q = QK + (rowbase + qrow0 + mf * 16 + ln) * LDQK + h * 64;
    qf[mf][0] = *(const s16x8*)(q + q4 * 8);
    qf[mf][1] = *(const s16x8*)(q + 32 + q4 * 8);
  }
  f32x4 o[2][4] = {};
  float lp[2] = {};                     // per-lane l partials (q = ln)

  const int srow = tid >> 2;            // 0..63
  const int scol = (tid & 3) * 16;      // 0,16,32,48

  const unsigned short* kgp = Kp  + (size_t)srow * LDQK + scol;
  const unsigned short* vgp = VTp + (size_t)srow * SEQ  + scol;
  u16x8 kr  = *(const u16x8*)kgp;
  u16x8 kr2 = *(const u16x8*)(kgp + 8);
  u16x8 vr  = *(const u16x8*)vgp;
  u16x8 vr2 = *(const u16x8*)(vgp + 8);

  for (int t = 0; t < SEQ / 64; ++t) {
    __syncthreads();
    *(u16x8*)(Ks + srow * 72 + scol)     = kr;
    *(u16x8*)(Ks + srow * 72 + scol + 8) = kr2;
    *(u16x8*)(Vs + srow * 72 + scol)     = vr;
    *(u16x8*)(Vs + srow * 72 + scol + 8) = vr2;
    __syncthreads();
    if (t + 1 < SEQ / 64) {             // register prefetch of next tile
      kgp += (size_t)64 * LDQK;
      vgp += 64;
      kr  = *(const u16x8*)kgp;
      kr2 = *(const u16x8*)(kgp + 8);
      vr  = *(const u16x8*)vgp;
      vr2 = *(const u16x8*)(vgp + 8);
    }
    // S^T = K Q'^T : A=K frags (m=key), B=Q frags (n=q). K shared across mf.
    f32x4 s4[2][4] = {};
#pragma unroll
    for (int ni = 0; ni < 4; ni++) {
      const unsigned short* kb = Ks + (ni * 16 + ln) * 72 + q4 * 8;
      s16x8 kf0 = *(const s16x8*)kb;
      s16x8 kf1 = *(const s16x8*)(kb + 32);
#pragma unroll
      for (int mf = 0; mf < 2; ++mf) {
        s4[mf][ni] = __builtin_amdgcn_mfma_f32_16x16x32_bf16(kf0, qf[mf][0], s4[mf][ni], 0, 0, 0);
        s4[mf][ni] = __builtin_amdgcn_mfma_f32_16x16x32_bf16(kf1, qf[mf][1], s4[mf][ni], 0, 0, 0);
      }
    }
    // p = exp2(s^T): all 16 values belong to q=ln. Pack straight into PV
    // A-frags: element j of pf[ks] = e[ni=2ks+(j>>2)][r=j&3]  (kappa-aligned).
    s16x8 pf[2][2];
#pragma unroll
    for (int mf = 0; mf < 2; ++mf) {
      float e[4][4];
      float ls = 0.f;
#pragma unroll
      for (int ni = 0; ni < 4; ni++)
#pragma unroll
        for (int r = 0; r < 4; ++r) {
          e[ni][r] = __builtin_amdgcn_exp2f(s4[mf][ni][r]);
          ls += e[ni][r];
        }
      lp[mf] += ls;
#pragma unroll
      for (int ks = 0; ks < 2; ++ks) {
        union { s16x8 v; unsigned u[4]; } pu;
        pu.u[0] = pack_bf2(e[2 * ks][0],     e[2 * ks][1]);
        pu.u[1] = pack_bf2(e[2 * ks][2],     e[2 * ks][3]);
        pu.u[2] = pack_bf2(e[2 * ks + 1][0], e[2 * ks + 1][1]);
        pu.u[3] = pack_bf2(e[2 * ks + 1][2], e[2 * ks + 1][3]);
        pf[mf][ks] = pu.v;
      }
    }
    // O += P V : A=P (regs), B=V frags (n=dk), shared across mf
#pragma unroll
    for (int ks = 0; ks < 2; ++ks)
#pragma unroll
      for (int ni = 0; ni < 4; ni++) {
        s16x8 vf = *(const s16x8*)(Vs + (ni * 16 + ln) * 72 + ks * 32 + q4 * 8);
#pragma unroll
        for (int mf = 0; mf < 2; ++mf)
          o[mf][ni] = __builtin_amdgcn_mfma_f32_16x16x32_bf16(pf[mf][ks], vf, o[mf][ni], 0, 0, 0);
      }
  }
  // l: sum the 4 q4-replicas (lanes ln, ln+16, ln+32, ln+48)
#pragma unroll
  for (int mf = 0; mf < 2; ++mf) {
    float l = lp[mf];
    l += __shfl_xor(l, 16, 64);
    l += __shfl_xor(l, 32, 64);
    lp[mf] = l;                         // full sum for q=ln, all q4 replicas
  }
#pragma unroll
  for (int mf = 0; mf < 2; ++mf)
#pragma unroll
    for (int r = 0; r < 4; ++r) {
      float lv = __shfl(lp[mf], q4 * 4 + r, 64);   // l of q-row q4*4+r
      float inv = 1.0f / lv;
      size_t row = rowbase + qrow0 + mf * 16 + q4 * 4 + r;
#pragma unroll
      for (int ni = 0; ni < 4; ni++)
        Oc[row * DMODEL + h * 64 + ni * 16 + ln] = f2bf(o[mf][ni][r] * inv);
    }
}

// out = Oc @ Wo^T : M=8192 N=512 K=512, tile 128x64 (512 blocks = 2/CU), f32.
__global__ __launch_bounds__(256, 3) void gemm_out(
    const unsigned short* __restrict__ A,
    const unsigned short* __restrict__ Bt,
    float* __restrict__ C)
{
  __shared__ unsigned short As[128 * 32];
  __shared__ unsigned short Bs[64 * 32];
  const int tid  = threadIdx.x;
  const int wave = tid >> 6, lane = tid & 63;
  const int q4 = lane >> 4, ln = lane & 15;
  const size_t bm = (size_t)blockIdx.x * 128;
  const size_t bn = (size_t)blockIdx.y * 64;
  const int wm = (wave >> 1) * 64, wn = (wave & 1) * 32;
  f32x4 acc[4][2] = {};
  const int srow = wave * 16 + (lane >> 2);
  const int scol = (lane & 3) * 8;

  u16x8 a0 = *(const u16x8*)(A  + (bm + srow)      * 512 + scol);
  u16x8 a1 = *(const u16x8*)(A  + (bm + 64 + srow) * 512 + scol);
  u16x8 b0 = *(const u16x8*)(Bt + (bn + srow)      * 512 + scol);

  for (int kt = 0; kt < 512; kt += 32) {
    __syncthreads();
    *(u16x8*)(As + srow * 32 + scol)        = a0;
    *(u16x8*)(As + (64 + srow) * 32 + scol) = a1;
    *(u16x8*)(Bs + srow * 32 + scol)        = b0;
    __syncthreads();
    if (kt + 32 < 512) {
      a0 = *(const u16x8*)(A  + (bm + srow)      * 512 + kt + 32 + scol);
      a1 = *(const u16x8*)(A  + (bm + 64 + srow) * 512 + kt + 32 + scol);
      b0 = *(const u16x8*)(Bt + (bn + srow)      * 512 + kt + 32 + scol);
    }
    s16x8 af[4], bfr[2];
#pragma unroll
    for (int i = 0; i < 4; i++)
      af[i] = *(const s16x8*)(As + (wm + i * 16 + ln) * 32 + q4 * 8);
#pragma unroll
    for (int i = 0; i < 2; i++)
      bfr[i] = *(const s16x8*)(Bs + (wn + i * 16 + ln) * 32 + q4 * 8);
#pragma unroll
    for (int mi = 0; mi < 4; mi++)
#pragma unroll
      for (int ni = 0; ni < 2; ni++)
        acc[mi][ni] = __builtin_amdgcn_mfma_f32_16x16x32_bf16(
            af[mi], bfr[ni], acc[mi][ni], 0, 0, 0);
  }
#pragma unroll
  for (int mi = 0; mi < 4; mi++)
#pragma unroll
    for (int r = 0; r < 4; ++r) {
      size_t row = bm + wm + mi * 16 + q4 * 4 + r;
#pragma unroll
      for (int ni = 0; ni < 2; ni++)
        C[row * 512 + bn + wn + ni * 16 + ln] = acc[mi][ni][r];
    }
}

extern "C" void kernel_launch(void* const* d_in, const int* in_sizes, int n_in,
                              void* d_out, int out_size, void* d_ws, size_t ws_size,
                              hipStream_t stream) {
  const float* x  = (const float*)d_in[0];
  const float* Wq = (const float*)d_in[1];
  const float* Wk = (const float*)d_in[2];
  const float* Wv = (const float*)d_in[3];
  const float* Wo = (const float*)d_in[4];

  char* ws = (char*)d_ws;
  unsigned short* xb   = (unsigned short*)(ws);              //  8,388,608
  unsigned short* Wall = (unsigned short*)(ws + 8388608);    //  2,097,152
  unsigned short* QKb  = (unsigned short*)(ws + 10485760);   // 16,777,216
  unsigned short* Vtb  = (unsigned short*)(ws + 27262976);   //  8,388,608
  unsigned short* Oc   = (unsigned short*)(ws + 35651584);   //  8,388,608

  const float C2 = 0.125f * 1.44269504088896f;  // 1/sqrt(64) * log2(e)

  hipLaunchKernelGGL(cast_x_kernel, dim3(NTOK * DMODEL / 4 / 256), dim3(256), 0,
                     stream, x, xb, NTOK * DMODEL / 4);
  hipLaunchKernelGGL(wtrans4_kernel, dim3(1024, 4), dim3(256), 0, stream,
                     Wq, Wk, Wv, Wo, Wall, C2);
  hipLaunchKernelGGL(gemm_qkv, dim3(64, 12), dim3(256), 0, stream,
                     xb, Wall, QKb, Vtb);
  hipLaunchKernelGGL(attn_kernel, dim3(32, 8, 2), dim3(256), 0, stream,
                     QKb, Vtb, Oc);
  hipLaunchKernelGGL(gemm_out, dim3(64, 8), dim3(256), 0, stream,
                     Oc, Wall + 3 * 262144, (float*)d_out);
}

// Round 7
// 195.601 us; speedup vs baseline: 1.1510x; 1.0552x over previous
//
#include <hip/hip_runtime.h>
#include <hip/hip_bf16.h>

// MultiHeadSelfAttention  B=2, S=4096, D=512, H=8, dk=64
// R7: (a) attn: double-buffered K/V LDS, ONE barrier per 64-key tile
//     (R6 was latency/barrier-bound: no pipe >57%), V-frags hoisted to regs.
//     (b) GEMMs: __builtin_amdgcn_global_load_lds width=16 staging (m97).
// S^T = K*Q^T trick: lane holds P for its own q-row; kappa key permutation
// baked into V^T global layout -> P packs in-register into PV A-frags.
// kappa(m) = 32*(m>>5) + 8*((m>>2)&3) + 4*((m>>4)&1) + (m&3)  per 64-group.

#define DMODEL 512
#define SEQ    4096
#define NTOK   8192
#define LDQK   1024

using f32x4 = __attribute__((ext_vector_type(4))) float;
using s16x8 = __attribute__((ext_vector_type(8))) short;
using u16x8 = __attribute__((ext_vector_type(8))) unsigned short;

static __device__ __forceinline__ unsigned short f2bf(float f) {
  union { float f; unsigned u; } v; v.f = f;
  unsigned r = v.u + 0x7fff + ((v.u >> 16) & 1);   // RNE
  return (unsigned short)(r >> 16);
}

static __device__ __forceinline__ unsigned pack_bf2(float lo, float hi) {
  __hip_bfloat162 t = __float22bfloat162_rn(make_float2(lo, hi));
  union { __hip_bfloat162 b; unsigned u; } c; c.b = t; return c.u;
}

// async global->LDS, 16B per lane; lds base must be wave-uniform, each lane
// deposits at base + lane*16B.
static __device__ __forceinline__ void gll16(const void* g, void* l) {
  __builtin_amdgcn_global_load_lds(
      (const __attribute__((address_space(1))) unsigned int*)g,
      (__attribute__((address_space(3))) unsigned int*)l, 16, 0, 0);
}

__global__ void cast_x_kernel(const float* __restrict__ x,
                              unsigned short* __restrict__ xb, int n4) {
  int i = blockIdx.x * blockDim.x + threadIdx.x;
  if (i >= n4) return;
  float4 v = ((const float4*)x)[i];
  ushort4 o;
  o.x = f2bf(v.x); o.y = f2bf(v.y); o.z = f2bf(v.z); o.w = f2bf(v.w);
  ((ushort4*)xb)[i] = o;
}

// All four W transposes in one launch. Wall = [Wq'|Wk|Wv|Wo], each N-major.
__global__ void wtrans4_kernel(const float* __restrict__ Wq,
                               const float* __restrict__ Wk,
                               const float* __restrict__ Wv,
                               const float* __restrict__ Wo,
                               unsigned short* __restrict__ Wall, float c2) {
  int y = blockIdx.y;
  int idx = blockIdx.x * 256 + threadIdx.x;
  const float* W = (y == 0) ? Wq : (y == 1) ? Wk : (y == 2) ? Wv : Wo;
  float scale = (y == 0) ? c2 : 1.0f;
  int k = idx & 511, n = idx >> 9;
  Wall[y * 262144 + idx] = f2bf(W[k * 512 + n] * scale);
}

// Fused QK + V^T GEMM. grid (64, 12). global_load_lds staging (m97 2-barrier).
//  by 0..7 : QK block  — C[8192 x 1024] = xb @ [Wq'|Wk]^T, bf16 row-major.
//  by 8..11: V^T block — C[512 x 8192] = Wv_t @ xb^T, stored batched
//            [b][m=h*64+dk][s] with kappa-permuted s within 64-groups.
__global__ __launch_bounds__(256, 3) void gemm_qkv(
    const unsigned short* __restrict__ xb,
    const unsigned short* __restrict__ Wall,
    unsigned short* __restrict__ QKb,
    unsigned short* __restrict__ Vtb)
{
  __shared__ unsigned short As[128 * 32];
  __shared__ unsigned short Bs[128 * 32];
  const int by = blockIdx.y;
  const bool vmode = (by >= 8);
  const unsigned short* A  = vmode ? (Wall + 2 * 262144) : xb;
  const unsigned short* Bt = vmode ? xb : Wall;
  const size_t bm = vmode ? (size_t)(by - 8) * 128 : (size_t)blockIdx.x * 128;
  const size_t bn = vmode ? (size_t)blockIdx.x * 128 : (size_t)by * 128;
  const int tid  = threadIdx.x;
  const int wave = tid >> 6, lane = tid & 63;
  const int q4 = lane >> 4, ln = lane & 15;
  const int wm = (wave >> 1) * 64, wn = (wave & 1) * 64;
  f32x4 acc[4][4] = {};
  const int srow = wave * 16 + (lane >> 2);   // staging: dest = tid*16B (lane-contig)
  const int scol = (lane & 3) * 8;

  const unsigned short* Ag  = A  + (bm + srow)      * 512 + scol;
  const unsigned short* Ag2 = A  + (bm + 64 + srow) * 512 + scol;
  const unsigned short* Bg  = Bt + (bn + srow)      * 512 + scol;
  const unsigned short* Bg2 = Bt + (bn + 64 + srow) * 512 + scol;
  unsigned short* Ad  = As + wave * 512;          // wave-uniform bases
  unsigned short* Ad2 = As + 2048 + wave * 512;
  unsigned short* Bd  = Bs + wave * 512;
  unsigned short* Bd2 = Bs + 2048 + wave * 512;

  for (int kt = 0; kt < 512; kt += 32) {
    __syncthreads();                     // LDS free (prev compute done)
    gll16(Ag + kt,  Ad);
    gll16(Ag2 + kt, Ad2);
    gll16(Bg + kt,  Bd);
    gll16(Bg2 + kt, Bd2);
    __syncthreads();                     // drains vmcnt -> data visible
    s16x8 af[4], bfr[4];
#pragma unroll
    for (int i = 0; i < 4; i++)
      af[i] = *(const s16x8*)(As + (wm + i * 16 + ln) * 32 + q4 * 8);
#pragma unroll
    for (int i = 0; i < 4; i++)
      bfr[i] = *(const s16x8*)(Bs + (wn + i * 16 + ln) * 32 + q4 * 8);
#pragma unroll
    for (int mi = 0; mi < 4; mi++)
#pragma unroll
      for (int ni = 0; ni < 4; ni++)
        acc[mi][ni] = __builtin_amdgcn_mfma_f32_16x16x32_bf16(
            af[mi], bfr[ni], acc[mi][ni], 0, 0, 0);
  }
#pragma unroll
  for (int mi = 0; mi < 4; mi++)
#pragma unroll
    for (int r = 0; r < 4; ++r) {
      size_t row = bm + wm + mi * 16 + q4 * 4 + r;
#pragma unroll
      for (int ni = 0; ni < 4; ni++) {
        size_t col = bn + wn + ni * 16 + ln;
        unsigned short hv = f2bf(acc[mi][ni][r]);
        if (!vmode) {
          QKb[row * 1024 + col] = hv;
        } else {
          int b = (int)(col >> 12), s = (int)(col & 4095);
          // kappa(s%64): position holding key s for PV A-frag alignment
          int sp = (s & ~63) | (s & 32) | (((s >> 2) & 3) << 3) |
                   (((s >> 4) & 1) << 2) | (s & 3);
          Vtb[(size_t)b * 2097152 + row * 4096 + sp] = hv;
        }
      }
    }
}

// Flash-lite attention. grid (32 qtiles x 128 rows, 8 heads, 2 batch) = 512.
// 4 waves x 32 q-rows. S^T = K*Q^T; P packed in-register into PV A-frags.
// Double-buffered K/V LDS, ONE barrier per tile; V-frags hoisted to regs.
__global__ __launch_bounds__(256, 2) void attn_kernel(
    const unsigned short* __restrict__ QK,   // NTOK x 1024 [Q'|K]
    const unsigned short* __restrict__ Vt,   // [b*8+h][64 dk][4096 s-kappa]
    unsigned short* __restrict__ Oc)         // NTOK x 512 concat
{
  const int qt = blockIdx.x, h = blockIdx.y, b = blockIdx.z;
  const int tid = threadIdx.x, wave = tid >> 6, lane = tid & 63;
  const int q4 = lane >> 4, ln = lane & 15;
  __shared__ unsigned short Ks[2][64 * 72];   // [buf][key][dk]
  __shared__ unsigned short Vs[2][64 * 72];   // [buf][dk][key-kappa]
  const size_t rowbase = (size_t)b * SEQ;
  const size_t qrow0   = (size_t)qt * 128 + wave * 32;
  const unsigned short* Kp  = QK + rowbase * LDQK + 512 + h * 64;
  const unsigned short* VTp = Vt + ((size_t)(b * 8 + h) * 64) * SEQ;

  s16x8 qf[2][2];   // B-frags: B[n=ln (q)][k=q4*8+j]
#pragma unroll
  for (int mf = 0; mf < 2; ++mf) {
    const unsigned short* q = QK + (rowbase + qrow0 + mf * 16 + ln) * LDQK + h * 64;
    qf[mf][0] = *(const s16x8*)(q + q4 * 8);
    qf[mf][1] = *(const s16x8*)(q + 32 + q4 * 8);
  }
  f32x4 o[2][4] = {};
  float lp[2] = {};                     // per-lane l partials (q = ln)

  const int srow = tid >> 2;            // 0..63
  const int scol = (tid & 3) * 16;      // 0,16,32,48

  const unsigned short* kgp = Kp  + (size_t)srow * LDQK + scol;
  const unsigned short* vgp = VTp + (size_t)srow * SEQ  + scol;

  // tile 0 -> regs -> buf0; prefetch tile 1 -> regs
  u16x8 kr  = *(const u16x8*)kgp;
  u16x8 kr2 = *(const u16x8*)(kgp + 8);
  u16x8 vr  = *(const u16x8*)vgp;
  u16x8 vr2 = *(const u16x8*)(vgp + 8);
  *(u16x8*)(Ks[0] + srow * 72 + scol)     = kr;
  *(u16x8*)(Ks[0] + srow * 72 + scol + 8) = kr2;
  *(u16x8*)(Vs[0] + srow * 72 + scol)     = vr;
  *(u16x8*)(Vs[0] + srow * 72 + scol + 8) = vr2;
  kgp += (size_t)64 * LDQK;  vgp += 64;
  kr  = *(const u16x8*)kgp;
  kr2 = *(const u16x8*)(kgp + 8);
  vr  = *(const u16x8*)vgp;
  vr2 = *(const u16x8*)(vgp + 8);
  __syncthreads();

  for (int t = 0; t < SEQ / 64; ++t) {
    const int cur = t & 1;
    const unsigned short* Kc = Ks[cur];
    const unsigned short* Vc = Vs[cur];

    // S^T = K Q'^T : A=K frags (m=key), B=Q frags (n=q). K shared across mf.
    f32x4 s4[2][4] = {};
#pragma unroll
    for (int ni = 0; ni < 4; ni++) {
      const unsigned short* kb = Kc + (ni * 16 + ln) * 72 + q4 * 8;
      s16x8 kf0 = *(const s16x8*)kb;
      s16x8 kf1 = *(const s16x8*)(kb + 32);
#pragma unroll
      for (int mf = 0; mf < 2; ++mf) {
        s4[mf][ni] = __builtin_amdgcn_mfma_f32_16x16x32_bf16(kf0, qf[mf][0], s4[mf][ni], 0, 0, 0);
        s4[mf][ni] = __builtin_amdgcn_mfma_f32_16x16x32_bf16(kf1, qf[mf][1], s4[mf][ni], 0, 0, 0);
      }
    }
    // hoist V frags (independent of exp2 chain)
    s16x8 vf[2][4];
#pragma unroll
    for (int ks = 0; ks < 2; ++ks)
#pragma unroll
      for (int ni = 0; ni < 4; ni++)
        vf[ks][ni] = *(const s16x8*)(Vc + (ni * 16 + ln) * 72 + ks * 32 + q4 * 8);

    // p = exp2(s^T): all 16 values belong to q=ln. Pack straight into PV
    // A-frags: element j of pf[ks] = e[ni=2ks+(j>>2)][r=j&3]  (kappa-aligned).
    s16x8 pf[2][2];
#pragma unroll
    for (int mf = 0; mf < 2; ++mf) {
      float e[4][4];
      float ls = 0.f;
#pragma unroll
      for (int ni = 0; ni < 4; ni++)
#pragma unroll
        for (int r = 0; r < 4; ++r) {
          e[ni][r] = __builtin_amdgcn_exp2f(s4[mf][ni][r]);
          ls += e[ni][r];
        }
      lp[mf] += ls;
#pragma unroll
      for (int ks = 0; ks < 2; ++ks) {
        union { s16x8 v; unsigned u[4]; } pu;
        pu.u[0] = pack_bf2(e[2 * ks][0],     e[2 * ks][1]);
        pu.u[1] = pack_bf2(e[2 * ks][2],     e[2 * ks][3]);
        pu.u[2] = pack_bf2(e[2 * ks + 1][0], e[2 * ks + 1][1]);
        pu.u[3] = pack_bf2(e[2 * ks + 1][2], e[2 * ks + 1][3]);
        pf[mf][ks] = pu.v;
      }
    }
    // O += P V
#pragma unroll
    for (int ks = 0; ks < 2; ++ks)
#pragma unroll
      for (int ni = 0; ni < 4; ni++)
#pragma unroll
        for (int mf = 0; mf < 2; ++mf)
          o[mf][ni] = __builtin_amdgcn_mfma_f32_16x16x32_bf16(pf[mf][ks], vf[ks][ni], o[mf][ni], 0, 0, 0);

    // stage tile t+1 into other buffer; prefetch tile t+2
    if (t + 1 < SEQ / 64) {
      unsigned short* Kn = Ks[cur ^ 1];
      unsigned short* Vn = Vs[cur ^ 1];
      *(u16x8*)(Kn + srow * 72 + scol)     = kr;
      *(u16x8*)(Kn + srow * 72 + scol + 8) = kr2;
      *(u16x8*)(Vn + srow * 72 + scol)     = vr;
      *(u16x8*)(Vn + srow * 72 + scol + 8) = vr2;
      if (t + 2 < SEQ / 64) {
        kgp += (size_t)64 * LDQK;  vgp += 64;
        kr  = *(const u16x8*)kgp;
        kr2 = *(const u16x8*)(kgp + 8);
        vr  = *(const u16x8*)vgp;
        vr2 = *(const u16x8*)(vgp + 8);
      }
    }
    __syncthreads();   // single barrier per tile
  }
  // l: sum the 4 q4-replicas (lanes ln, ln+16, ln+32, ln+48)
#pragma unroll
  for (int mf = 0; mf < 2; ++mf) {
    float l = lp[mf];
    l += __shfl_xor(l, 16, 64);
    l += __shfl_xor(l, 32, 64);
    lp[mf] = l;
  }
#pragma unroll
  for (int mf = 0; mf < 2; ++mf)
#pragma unroll
    for (int r = 0; r < 4; ++r) {
      float lv = __shfl(lp[mf], q4 * 4 + r, 64);   // l of q-row q4*4+r
      float inv = 1.0f / lv;
      size_t row = rowbase + qrow0 + mf * 16 + q4 * 4 + r;
#pragma unroll
      for (int ni = 0; ni < 4; ni++)
        Oc[row * DMODEL + h * 64 + ni * 16 + ln] = f2bf(o[mf][ni][r] * inv);
    }
}

// out = Oc @ Wo^T : M=8192 N=512 K=512, tile 128x64 (512 blocks = 2/CU), f32.
__global__ __launch_bounds__(256, 3) void gemm_out(
    const unsigned short* __restrict__ A,
    const unsigned short* __restrict__ Bt,
    float* __restrict__ C)
{
  __shared__ unsigned short As[128 * 32];
  __shared__ unsigned short Bs[64 * 32];
  const int tid  = threadIdx.x;
  const int wave = tid >> 6, lane = tid & 63;
  const int q4 = lane >> 4, ln = lane & 15;
  const size_t bm = (size_t)blockIdx.x * 128;
  const size_t bn = (size_t)blockIdx.y * 64;
  const int wm = (wave >> 1) * 64, wn = (wave & 1) * 32;
  f32x4 acc[4][2] = {};
  const int srow = wave * 16 + (lane >> 2);
  const int scol = (lane & 3) * 8;

  const unsigned short* Ag  = A  + (bm + srow)      * 512 + scol;
  const unsigned short* Ag2 = A  + (bm + 64 + srow) * 512 + scol;
  const unsigned short* Bg  = Bt + (bn + srow)      * 512 + scol;
  unsigned short* Ad  = As + wave * 512;
  unsigned short* Ad2 = As + 2048 + wave * 512;
  unsigned short* Bd  = Bs + wave * 512;

  for (int kt = 0; kt < 512; kt += 32) {
    __syncthreads();
    gll16(Ag + kt,  Ad);
    gll16(Ag2 + kt, Ad2);
    gll16(Bg + kt,  Bd);
    __syncthreads();
    s16x8 af[4], bfr[2];
#pragma unroll
    for (int i = 0; i < 4; i++)
      af[i] = *(const s16x8*)(As + (wm + i * 16 + ln) * 32 + q4 * 8);
#pragma unroll
    for (int i = 0; i < 2; i++)
      bfr[i] = *(const s16x8*)(Bs + (wn + i * 16 + ln) * 32 + q4 * 8);
#pragma unroll
    for (int mi = 0; mi < 4; mi++)
#pragma unroll
      for (int ni = 0; ni < 2; ni++)
        acc[mi][ni] = __builtin_amdgcn_mfma_f32_16x16x32_bf16(
            af[mi], bfr[ni], acc[mi][ni], 0, 0, 0);
  }
#pragma unroll
  for (int mi = 0; mi < 4; mi++)
#pragma unroll
    for (int r = 0; r < 4; ++r) {
      size_t row = bm + wm + mi * 16 + q4 * 4 + r;
#pragma unroll
      for (int ni = 0; ni < 2; ni++)
        C[row * 512 + bn + wn + ni * 16 + ln] = acc[mi][ni][r];
    }
}

extern "C" void kernel_launch(void* const* d_in, const int* in_sizes, int n_in,
                              void* d_out, int out_size, void* d_ws, size_t ws_size,
                              hipStream_t stream) {
  const float* x  = (const float*)d_in[0];
  const float* Wq = (const float*)d_in[1];
  const float* Wk = (const float*)d_in[2];
  const float* Wv = (const float*)d_in[3];
  const float* Wo = (const float*)d_in[4];

  char* ws = (char*)d_ws;
  unsigned short* xb   = (unsigned short*)(ws);              //  8,388,608
  unsigned short* Wall = (unsigned short*)(ws + 8388608);    //  2,097,152
  unsigned short* QKb  = (unsigned short*)(ws + 10485760);   // 16,777,216
  unsigned short* Vtb  = (unsigned short*)(ws + 27262976);   //  8,388,608
  unsigned short* Oc   = (unsigned short*)(ws + 35651584);   //  8,388,608

  const float C2 = 0.125f * 1.44269504088896f;  // 1/sqrt(64) * log2(e)

  hipLaunchKernelGGL(cast_x_kernel, dim3(NTOK * DMODEL / 4 / 256), dim3(256), 0,
                     stream, x, xb, NTOK * DMODEL / 4);
  hipLaunchKernelGGL(wtrans4_kernel, dim3(1024, 4), dim3(256), 0, stream,
                     Wq, Wk, Wv, Wo, Wall, C2);
  hipLaunchKernelGGL(gemm_qkv, dim3(64, 12), dim3(256), 0, stream,
                     xb, Wall, QKb, Vtb);
  hipLaunchKernelGGL(attn_kernel, dim3(32, 8, 2), dim3(256), 0, stream,
                     QKb, Vtb, Oc);
  hipLaunchKernelGGL(gemm_out, dim3(64, 8), dim3(256), 0, stream,
                     Oc, Wall + 3 * 262144, (float*)d_out);
}

// Round 8
// 192.486 us; speedup vs baseline: 1.1697x; 1.0162x over previous
//
#include <hip/hip_runtime.h>
#include <hip/hip_bf16.h>

// MultiHeadSelfAttention  B=2, S=4096, D=512, H=8, dk=64
// R8: attn waves split 2x2 over (q, keys): wave (wq,wk) = 64 q-rows x 32 keys
//     of each 64-key tile -> K/V frag reads cover only own keys: LDS ops
//     20 -> 12 per lane-tile. O/l partials over key-halves reduced ONCE at
//     kernel end via LDS (no-max softmax is associative over keys).
//     S^T=K*Q^T in-register P packing retained; key perm sigma == R7 kappa
//     (bit-identical) -> gemm_qkv V^T layout unchanged.
//     wtrans4: tiled LDS transpose (old version read W at stride 2KB).

#define DMODEL 512
#define SEQ    4096
#define NTOK   8192
#define LDQK   1024

using f32x4 = __attribute__((ext_vector_type(4))) float;
using s16x8 = __attribute__((ext_vector_type(8))) short;
using u16x8 = __attribute__((ext_vector_type(8))) unsigned short;

static __device__ __forceinline__ unsigned short f2bf(float f) {
  union { float f; unsigned u; } v; v.f = f;
  unsigned r = v.u + 0x7fff + ((v.u >> 16) & 1);   // RNE
  return (unsigned short)(r >> 16);
}

static __device__ __forceinline__ unsigned pack_bf2(float lo, float hi) {
  __hip_bfloat162 t = __float22bfloat162_rn(make_float2(lo, hi));
  union { __hip_bfloat162 b; unsigned u; } c; c.b = t; return c.u;
}

// async global->LDS, 16B per lane; lds base wave-uniform, lane i -> base+16i.
static __device__ __forceinline__ void gll16(const void* g, void* l) {
  __builtin_amdgcn_global_load_lds(
      (const __attribute__((address_space(1))) unsigned int*)g,
      (__attribute__((address_space(3))) unsigned int*)l, 16, 0, 0);
}

__global__ void cast_x_kernel(const float* __restrict__ x,
                              unsigned short* __restrict__ xb, int n4) {
  int i = blockIdx.x * blockDim.x + threadIdx.x;
  if (i >= n4) return;
  float4 v = ((const float4*)x)[i];
  ushort4 o;
  o.x = f2bf(v.x); o.y = f2bf(v.y); o.z = f2bf(v.z); o.w = f2bf(v.w);
  ((ushort4*)xb)[i] = o;
}

// Tiled transpose: Wall[y][n*512+k] = bf16(W[k*512+n] * scale). grid (64,4).
__global__ void wtrans4_kernel(const float* __restrict__ Wq,
                               const float* __restrict__ Wk,
                               const float* __restrict__ Wv,
                               const float* __restrict__ Wo,
                               unsigned short* __restrict__ Wall, float c2) {
  __shared__ float T[64][65];
  const int y = blockIdx.y;
  const float* W = (y == 0) ? Wq : (y == 1) ? Wk : (y == 2) ? Wv : Wo;
  const float scale = (y == 0) ? c2 : 1.0f;
  const int tk = (blockIdx.x & 7) * 64;    // k-tile base
  const int tn = (blockIdx.x >> 3) * 64;   // n-tile base
  const int r  = threadIdx.x >> 2;
  const int cq = threadIdx.x & 3;
#pragma unroll
  for (int i = 0; i < 4; ++i) {
    int c = (cq + 4 * i) * 4;              // contiguous float4 along the row
    float4 v = *(const float4*)&W[(size_t)(tk + r) * 512 + tn + c];
    T[r][c + 0] = v.x * scale; T[r][c + 1] = v.y * scale;
    T[r][c + 2] = v.z * scale; T[r][c + 3] = v.w * scale;
  }
  __syncthreads();
  const int n  = threadIdx.x >> 2;
  const int k0 = (threadIdx.x & 3) * 16;
#pragma unroll
  for (int j4 = 0; j4 < 4; ++j4) {
    ushort4 o;
    o.x = f2bf(T[k0 + j4 * 4 + 0][n]);
    o.y = f2bf(T[k0 + j4 * 4 + 1][n]);
    o.z = f2bf(T[k0 + j4 * 4 + 2][n]);
    o.w = f2bf(T[k0 + j4 * 4 + 3][n]);
    *(ushort4*)&Wall[(size_t)y * 262144 + (size_t)(tn + n) * 512 + tk + k0 + j4 * 4] = o;
  }
}

// Fused QK + V^T GEMM. grid (64, 12). global_load_lds staging (m97 2-barrier).
//  by 0..7 : QK block  — C[8192 x 1024] = xb @ [Wq'|Wk]^T, bf16 row-major.
//  by 8..11: V^T block — C[512 x 8192] = Wv_t @ xb^T, stored batched
//            [b][m=h*64+dk][s] with kappa-permuted s within 64-groups.
__global__ __launch_bounds__(256, 3) void gemm_qkv(
    const unsigned short* __restrict__ xb,
    const unsigned short* __restrict__ Wall,
    unsigned short* __restrict__ QKb,
    unsigned short* __restrict__ Vtb)
{
  __shared__ unsigned short As[128 * 32];
  __shared__ unsigned short Bs[128 * 32];
  const int by = blockIdx.y;
  const bool vmode = (by >= 8);
  const unsigned short* A  = vmode ? (Wall + 2 * 262144) : xb;
  const unsigned short* Bt = vmode ? xb : Wall;
  const size_t bm = vmode ? (size_t)(by - 8) * 128 : (size_t)blockIdx.x * 128;
  const size_t bn = vmode ? (size_t)blockIdx.x * 128 : (size_t)by * 128;
  const int tid  = threadIdx.x;
  const int wave = tid >> 6, lane = tid & 63;
  const int q4 = lane >> 4, ln = lane & 15;
  const int wm = (wave >> 1) * 64, wn = (wave & 1) * 64;
  f32x4 acc[4][4] = {};
  const int srow = wave * 16 + (lane >> 2);
  const int scol = (lane & 3) * 8;

  const unsigned short* Ag  = A  + (bm + srow)      * 512 + scol;
  const unsigned short* Ag2 = A  + (bm + 64 + srow) * 512 + scol;
  const unsigned short* Bg  = Bt + (bn + srow)      * 512 + scol;
  const unsigned short* Bg2 = Bt + (bn + 64 + srow) * 512 + scol;
  unsigned short* Ad  = As + wave * 512;
  unsigned short* Ad2 = As + 2048 + wave * 512;
  unsigned short* Bd  = Bs + wave * 512;
  unsigned short* Bd2 = Bs + 2048 + wave * 512;

  for (int kt = 0; kt < 512; kt += 32) {
    __syncthreads();
    gll16(Ag + kt,  Ad);
    gll16(Ag2 + kt, Ad2);
    gll16(Bg + kt,  Bd);
    gll16(Bg2 + kt, Bd2);
    __syncthreads();
    s16x8 af[4], bfr[4];
#pragma unroll
    for (int i = 0; i < 4; i++)
      af[i] = *(const s16x8*)(As + (wm + i * 16 + ln) * 32 + q4 * 8);
#pragma unroll
    for (int i = 0; i < 4; i++)
      bfr[i] = *(const s16x8*)(Bs + (wn + i * 16 + ln) * 32 + q4 * 8);
#pragma unroll
    for (int mi = 0; mi < 4; mi++)
#pragma unroll
      for (int ni = 0; ni < 4; ni++)
        acc[mi][ni] = __builtin_amdgcn_mfma_f32_16x16x32_bf16(
            af[mi], bfr[ni], acc[mi][ni], 0, 0, 0);
  }
#pragma unroll
  for (int mi = 0; mi < 4; mi++)
#pragma unroll
    for (int r = 0; r < 4; ++r) {
      size_t row = bm + wm + mi * 16 + q4 * 4 + r;
#pragma unroll
      for (int ni = 0; ni < 4; ni++) {
        size_t col = bn + wn + ni * 16 + ln;
        unsigned short hv = f2bf(acc[mi][ni][r]);
        if (!vmode) {
          QKb[row * 1024 + col] = hv;
        } else {
          int b = (int)(col >> 12), s = (int)(col & 4095);
          // kappa(s%64): slot holding key s for PV A-frag alignment
          int sp = (s & ~63) | (s & 32) | (((s >> 2) & 3) << 3) |
                   (((s >> 4) & 1) << 2) | (s & 3);
          Vtb[(size_t)b * 2097152 + row * 4096 + sp] = hv;
        }
      }
    }
}

// Flash-lite attention. grid (32, 8, 2) = 512 blocks, 256 thr.
// Waves 2x2: wq in {0,1} -> q-rows [wq*64, wq*64+64); wk in {0,1} -> keys
// [wk*32, wk*32+32) of each 64-key tile. S^T = K*Q^T (lane's C col = its own
// q); P packed in-register into PV A-frags via sigma==kappa key slots.
// O/l key-half partials reduced once at end via LDS; 1 barrier per tile.
__global__ __launch_bounds__(256, 2) void attn_kernel(
    const unsigned short* __restrict__ QK,   // NTOK x 1024 [Q'|K]
    const unsigned short* __restrict__ Vt,   // [b*8+h][64 dk][4096 s-kappa]
    unsigned short* __restrict__ Oc)         // NTOK x 512 concat
{
  const int qt = blockIdx.x, h = blockIdx.y, b = blockIdx.z;
  const int tid = threadIdx.x, wave = tid >> 6, lane = tid & 63;
  const int q4 = lane >> 4, ln = lane & 15;
  const int wq = wave >> 1, wk = wave & 1;
  __shared__ __align__(16) unsigned char SM[36864];
  unsigned short* KsB = (unsigned short*)SM;            // [2][64*72]
  unsigned short* VsB = (unsigned short*)(SM + 18432);  // [2][64*72]
  const size_t rowbase = (size_t)b * SEQ;
  const size_t qrow0   = (size_t)qt * 128 + wq * 64;
  const unsigned short* Kp  = QK + rowbase * LDQK + 512 + h * 64;
  const unsigned short* VTp = Vt + ((size_t)(b * 8 + h) * 64) * SEQ;

  s16x8 qf[4][2];   // B-frags: q = qrow0 + nt*16 + ln, dk chunk c
#pragma unroll
  for (int nt = 0; nt < 4; ++nt) {
    const unsigned short* q = QK + (rowbase + qrow0 + nt * 16 + ln) * LDQK + h * 64;
    qf[nt][0] = *(const s16x8*)(q + q4 * 8);
    qf[nt][1] = *(const s16x8*)(q + 32 + q4 * 8);
  }
  f32x4 o[4][4] = {};   // [nt(q)][dt(dk)] partial over wk's keys
  float lp[4] = {};     // l partial for q = nt*16+ln

  const int srow = tid >> 2;            // 0..63
  const int scol = (tid & 3) * 16;      // 0,16,32,48

  const unsigned short* kgp = Kp  + (size_t)srow * LDQK + scol;
  const unsigned short* vgp = VTp + (size_t)srow * SEQ  + scol;

  u16x8 kr  = *(const u16x8*)kgp;
  u16x8 kr2 = *(const u16x8*)(kgp + 8);
  u16x8 vr  = *(const u16x8*)vgp;
  u16x8 vr2 = *(const u16x8*)(vgp + 8);
  *(u16x8*)(KsB + srow * 72 + scol)     = kr;
  *(u16x8*)(KsB + srow * 72 + scol + 8) = kr2;
  *(u16x8*)(VsB + srow * 72 + scol)     = vr;
  *(u16x8*)(VsB + srow * 72 + scol + 8) = vr2;
  kgp += (size_t)64 * LDQK;  vgp += 64;
  kr  = *(const u16x8*)kgp;
  kr2 = *(const u16x8*)(kgp + 8);
  vr  = *(const u16x8*)vgp;
  vr2 = *(const u16x8*)(vgp + 8);
  __syncthreads();

  for (int t = 0; t < SEQ / 64; ++t) {
    const int cur = t & 1;
    const unsigned short* Kc = KsB + cur * 4608;
    const unsigned short* Vc = VsB + cur * 4608;

    // S^T: A = K[m=key: wk*32+mi*16+ln][k=dk], B = Q[n=q][k=dk]
    f32x4 s4[2][4] = {};
#pragma unroll
    for (int mi = 0; mi < 2; ++mi)
#pragma unroll
      for (int c = 0; c < 2; ++c) {
        s16x8 kf = *(const s16x8*)(Kc + (wk * 32 + mi * 16 + ln) * 72 + c * 32 + q4 * 8);
#pragma unroll
        for (int nt = 0; nt < 4; ++nt)
          s4[mi][nt] = __builtin_amdgcn_mfma_f32_16x16x32_bf16(kf, qf[nt][c], s4[mi][nt], 0, 0, 0);
      }
    // V B-frags: B[k=slot wk*32+q4*8+j][n=dk dt*16+ln]
    s16x8 vf[4];
#pragma unroll
    for (int dt = 0; dt < 4; ++dt)
      vf[dt] = *(const s16x8*)(Vc + (dt * 16 + ln) * 72 + wk * 32 + q4 * 8);

    // p = exp2(s^T): lane's 8 values per nt all for q=nt*16+ln at keys
    // wk*32 + mi*16 + q4*4 + r -> slot 8*q4 + 4*mi + r -> A-frag elem j=4mi+r.
    s16x8 pf[4];
#pragma unroll
    for (int nt = 0; nt < 4; ++nt) {
      float e00 = __builtin_amdgcn_exp2f(s4[0][nt][0]);
      float e01 = __builtin_amdgcn_exp2f(s4[0][nt][1]);
      float e02 = __builtin_amdgcn_exp2f(s4[0][nt][2]);
      float e03 = __builtin_amdgcn_exp2f(s4[0][nt][3]);
      float e10 = __builtin_amdgcn_exp2f(s4[1][nt][0]);
      float e11 = __builtin_amdgcn_exp2f(s4[1][nt][1]);
      float e12 = __builtin_amdgcn_exp2f(s4[1][nt][2]);
      float e13 = __builtin_amdgcn_exp2f(s4[1][nt][3]);
      lp[nt] += ((e00 + e01) + (e02 + e03)) + ((e10 + e11) + (e12 + e13));
      union { s16x8 v; unsigned u[4]; } pu;
      pu.u[0] = pack_bf2(e00, e01);
      pu.u[1] = pack_bf2(e02, e03);
      pu.u[2] = pack_bf2(e10, e11);
      pu.u[3] = pack_bf2(e12, e13);
      pf[nt] = pu.v;
    }
    // O += P V over the wave's 32 keys (K=32 in one MFMA)
#pragma unroll
    for (int nt = 0; nt < 4; ++nt)
#pragma unroll
      for (int dt = 0; dt < 4; ++dt)
        o[nt][dt] = __builtin_amdgcn_mfma_f32_16x16x32_bf16(pf[nt], vf[dt], o[nt][dt], 0, 0, 0);

    if (t + 1 < SEQ / 64) {
      unsigned short* Kn = KsB + (cur ^ 1) * 4608;
      unsigned short* Vn = VsB + (cur ^ 1) * 4608;
      *(u16x8*)(Kn + srow * 72 + scol)     = kr;
      *(u16x8*)(Kn + srow * 72 + scol + 8) = kr2;
      *(u16x8*)(Vn + srow * 72 + scol)     = vr;
      *(u16x8*)(Vn + srow * 72 + scol + 8) = vr2;
      if (t + 2 < SEQ / 64) {
        kgp += (size_t)64 * LDQK;  vgp += 64;
        kr  = *(const u16x8*)kgp;
        kr2 = *(const u16x8*)(kgp + 8);
        vr  = *(const u16x8*)vgp;
        vr2 = *(const u16x8*)(vgp + 8);
      }
    }
    __syncthreads();   // single barrier per tile
  }

  // intra-wave l: sum q4 replicas (keys split across q4 lane groups)
#pragma unroll
  for (int nt = 0; nt < 4; ++nt) {
    lp[nt] += __shfl_xor(lp[nt], 16, 64);
    lp[nt] += __shfl_xor(lp[nt], 32, 64);
  }
  // cross-wave (wk) reduction of O and l via LDS (K/V buffers reused)
  float* Red  = (float*)SM;            // 32KB: [wq*16+nt*4+dt][lane] f32x4
  float* RedL = (float*)(SM + 32768);  // 2KB : [wq*4+nt][lane]
  if (wk == 1) {
#pragma unroll
    for (int nt = 0; nt < 4; ++nt) {
#pragma unroll
      for (int dt = 0; dt < 4; ++dt)
        *(f32x4*)(Red + ((wq * 16 + nt * 4 + dt) * 64 + lane) * 4) = o[nt][dt];
      RedL[(wq * 4 + nt) * 64 + lane] = lp[nt];
    }
  }
  __syncthreads();
  if (wk == 0) {
#pragma unroll
    for (int nt = 0; nt < 4; ++nt) {
#pragma unroll
      for (int dt = 0; dt < 4; ++dt)
        o[nt][dt] += *(const f32x4*)(Red + ((wq * 16 + nt * 4 + dt) * 64 + lane) * 4);
      lp[nt] += RedL[(wq * 4 + nt) * 64 + lane];
    }
#pragma unroll
    for (int nt = 0; nt < 4; ++nt)
#pragma unroll
      for (int r = 0; r < 4; ++r) {
        float lv = __shfl(lp[nt], q4 * 4 + r, 64);   // l of q-row nt*16+q4*4+r
        float inv = 1.0f / lv;
        size_t row = rowbase + qrow0 + nt * 16 + q4 * 4 + r;
#pragma unroll
        for (int dt = 0; dt < 4; ++dt)
          Oc[row * DMODEL + h * 64 + dt * 16 + ln] = f2bf(o[nt][dt][r] * inv);
      }
  }
}

// out = Oc @ Wo^T : M=8192 N=512 K=512, tile 128x64 (512 blocks = 2/CU), f32.
__global__ __launch_bounds__(256, 3) void gemm_out(
    const unsigned short* __restrict__ A,
    const unsigned short* __restrict__ Bt,
    float* __restrict__ C)
{
  __shared__ unsigned short As[128 * 32];
  __shared__ unsigned short Bs[64 * 32];
  const int tid  = threadIdx.x;
  const int wave = tid >> 6, lane = tid & 63;
  const int q4 = lane >> 4, ln = lane & 15;
  const size_t bm = (size_t)blockIdx.x * 128;
  const size_t bn = (size_t)blockIdx.y * 64;
  const int wm = (wave >> 1) * 64, wn = (wave & 1) * 32;
  f32x4 acc[4][2] = {};
  const int srow = wave * 16 + (lane >> 2);
  const int scol = (lane & 3) * 8;

  const unsigned short* Ag  = A  + (bm + srow)      * 512 + scol;
  const unsigned short* Ag2 = A  + (bm + 64 + srow) * 512 + scol;
  const unsigned short* Bg  = Bt + (bn + srow)      * 512 + scol;
  unsigned short* Ad  = As + wave * 512;
  unsigned short* Ad2 = As + 2048 + wave * 512;
  unsigned short* Bd  = Bs + wave * 512;

  for (int kt = 0; kt < 512; kt += 32) {
    __syncthreads();
    gll16(Ag + kt,  Ad);
    gll16(Ag2 + kt, Ad2);
    gll16(Bg + kt,  Bd);
    __syncthreads();
    s16x8 af[4], bfr[2];
#pragma unroll
    for (int i = 0; i < 4; i++)
      af[i] = *(const s16x8*)(As + (wm + i * 16 + ln) * 32 + q4 * 8);
#pragma unroll
    for (int i = 0; i < 2; i++)
      bfr[i] = *(const s16x8*)(Bs + (wn + i * 16 + ln) * 32 + q4 * 8);
#pragma unroll
    for (int mi = 0; mi < 4; mi++)
#pragma unroll
      for (int ni = 0; ni < 2; ni++)
        acc[mi][ni] = __builtin_amdgcn_mfma_f32_16x16x32_bf16(
            af[mi], bfr[ni], acc[mi][ni], 0, 0, 0);
  }
#pragma unroll
  for (int mi = 0; mi < 4; mi++)
#pragma unroll
    for (int r = 0; r < 4; ++r) {
      size_t row = bm + wm + mi * 16 + q4 * 4 + r;
#pragma unroll
      for (int ni = 0; ni < 2; ni++)
        C[row * 512 + bn + wn + ni * 16 + ln] = acc[mi][ni][r];
    }
}

extern "C" void kernel_launch(void* const* d_in, const int* in_sizes, int n_in,
                              void* d_out, int out_size, void* d_ws, size_t ws_size,
                              hipStream_t stream) {
  const float* x  = (const float*)d_in[0];
  const float* Wq = (const float*)d_in[1];
  const float* Wk = (const float*)d_in[2];
  const float* Wv = (const float*)d_in[3];
  const float* Wo = (const float*)d_in[4];

  char* ws = (char*)d_ws;
  unsigned short* xb   = (unsigned short*)(ws);              //  8,388,608
  unsigned short* Wall = (unsigned short*)(ws + 8388608);    //  2,097,152
  unsigned short* QKb  = (unsigned short*)(ws + 10485760);   // 16,777,216
  unsigned short* Vtb  = (unsigned short*)(ws + 27262976);   //  8,388,608
  unsigned short* Oc   = (unsigned short*)(ws + 35651584);   //  8,388,608

  const float C2 = 0.125f * 1.44269504088896f;  // 1/sqrt(64) * log2(e)

  hipLaunchKernelGGL(cast_x_kernel, dim3(NTOK * DMODEL / 4 / 256), dim3(256), 0,
                     stream, x, xb, NTOK * DMODEL / 4);
  hipLaunchKernelGGL(wtrans4_kernel, dim3(64, 4), dim3(256), 0, stream,
                     Wq, Wk, Wv, Wo, Wall, C2);
  hipLaunchKernelGGL(gemm_qkv, dim3(64, 12), dim3(256), 0, stream,
                     xb, Wall, QKb, Vtb);
  hipLaunchKernelGGL(attn_kernel, dim3(32, 8, 2), dim3(256), 0, stream,
                     QKb, Vtb, Oc);
  hipLaunchKernelGGL(gemm_out, dim3(64, 8), dim3(256), 0, stream,
                     Oc, Wall + 3 * 262144, (float*)d_out);
}